// Round 3
// baseline (98.177 us; speedup 1.0000x reference)
//
#include <hip/hip_runtime.h>

// FitStepOutput: per-row exclusive-prefix cumsum of (1-2*x), argmin (first-min
// tie-break), midpoint of surrounding bin edges.
//
// R3: global_load_lds (width=16) staging — no VGPR round-trip, no ds_write.
// LDS dest is linear (wave-uniform base + lane*16, required by HW); the
// bank-conflict XOR swizzle is applied to the per-lane GLOBAL source address
// (involution => source-permute == read-permute, rule #21 / m173).
// ROWS=128 -> 32 KB LDS -> 5 blocks/CU for barrier-stall overlap.
// Scan stays thread-per-row, sequential fp32, bit-exact vs np.cumsum.

#define NBINS  128
#define ROWS   128          // rows per block == threads per block (2 waves)
#define CHUNK  32           // columns per chunk
#define NCHUNK (NBINS / CHUNK)

__global__ __launch_bounds__(ROWS) void fitstep_kernel(
    const float* __restrict__ inp,
    const float* __restrict__ bins,
    float* __restrict__ out,
    int nrows)
{
    __shared__ float lds[2][ROWS * CHUNK];   // 2 x 16 KB = 32 KB

    const int t = threadIdx.x;
    const size_t rowbase = (size_t)blockIdx.x * ROWS;

    if (rowbase + ROWS <= (size_t)nrows) {
        const char* base = (const char*)(inp + rowbase * NBINS);

        // Per-thread constants for staging:
        //   flat slot f = i*128 + t  ->  row r = f>>3 = (t>>3) + 16*i,
        //   dest 16B-slot k' = f&7 = t&7 (constant across i),
        //   source slot j = k' ^ (r&7) = (t&7) ^ ((t>>3)&7)  (16*i: no effect
        //   on r&7... note 16*i changes r&7? 16*i mod 8 == 0, so no).
        const int r0   = t >> 3;
        const int jswz = (t & 7) ^ (r0 & 7);
        const size_t goff0 = (size_t)r0 * (NBINS * 4) + (size_t)jswz * 16;

        // stage chunk c into lds[buf]: 8 x global_load_lds, 16B/lane each.
        // LDS dest byte = (i*128 + t)*16  == wave-uniform + lane*16.  ✓
        auto stage = [&](int c, int buf) {
            const char* gc = base + goff0 + (size_t)c * (CHUNK * 4);
            #pragma unroll
            for (int i = 0; i < 8; ++i) {
                __builtin_amdgcn_global_load_lds(
                    (const __attribute__((address_space(1))) unsigned int*)
                        (gc + (size_t)i * 16 * (NBINS * 4)),   // +16 rows
                    (__attribute__((address_space(3))) unsigned int*)
                        (&lds[buf][(i * ROWS + t) * 4]),
                    16, 0, 0);
            }
        };

        stage(0, 0);
        __syncthreads();   // vmcnt(0) drain + barrier: chunk 0 ready

        float score = 0.0f, best = 0.0f;
        int bestIdx = 0;

        for (int c = 0; c < NCHUNK; ++c) {
            const int buf = c & 1;

            // prefetch next chunk into the other buffer (freed by the barrier
            // at the end of the previous iteration)
            if (c + 1 < NCHUNK) stage(c + 1, buf ^ 1);

            // scan 32 columns of row t from LDS, exact np.cumsum order,
            // strict < keeps FIRST minimum (np.argmin semantics).
            #pragma unroll
            for (int j = 0; j < 8; ++j) {
                const int slot = j ^ (t & 7);       // read-side of the swizzle
                float4 v = *reinterpret_cast<const float4*>(
                    &lds[buf][t * CHUNK + slot * 4]);
                int colbase = c * CHUNK + j * 4;
                score += (1.0f - 2.0f * v.x);
                if (score < best) { best = score; bestIdx = colbase + 1; }
                score += (1.0f - 2.0f * v.y);
                if (score < best) { best = score; bestIdx = colbase + 2; }
                score += (1.0f - 2.0f * v.z);
                if (score < best) { best = score; bestIdx = colbase + 3; }
                score += (1.0f - 2.0f * v.w);
                if (score < best) { best = score; bestIdx = colbase + 4; }
            }

            // barrier: (a) ensures chunk c+1 loads landed (syncthreads drains
            // each wave's vmcnt first), (b) frees lds[buf] for chunk c+2.
            if (c + 1 < NCHUNK) __syncthreads();
        }

        int lo = bestIdx - 1; if (lo < 0) lo = 0;
        int hi = bestIdx;     if (hi > NBINS - 1) hi = NBINS - 1;
        out[rowbase + t] = (bins[lo] + bins[hi]) * 0.5f;
    } else {
        // tail fallback (not hit for B = 1M = 8192 * 128)
        size_t row = rowbase + t;
        if (row >= (size_t)nrows) return;
        const float* rp = inp + row * NBINS;
        float score = 0.0f, best = 0.0f;
        int bestIdx = 0;
        for (int j = 0; j < NBINS; ++j) {
            score += (1.0f - 2.0f * rp[j]);
            if (score < best) { best = score; bestIdx = j + 1; }
        }
        int lo = bestIdx - 1; if (lo < 0) lo = 0;
        int hi = bestIdx;     if (hi > NBINS - 1) hi = NBINS - 1;
        out[row] = (bins[lo] + bins[hi]) * 0.5f;
    }
}

extern "C" void kernel_launch(void* const* d_in, const int* in_sizes, int n_in,
                              void* d_out, int out_size, void* d_ws, size_t ws_size,
                              hipStream_t stream)
{
    const float* inp  = (const float*)d_in[0];
    const float* bins = (const float*)d_in[1];
    float* out = (float*)d_out;

    int nrows = in_sizes[0] / NBINS;   // B = 1048576
    int grid  = (nrows + ROWS - 1) / ROWS;

    fitstep_kernel<<<grid, ROWS, 0, stream>>>(inp, bins, out, nrows);
}

// Round 4
// 98.096 us; speedup vs baseline: 1.0008x; 1.0008x over previous
//
#include <hip/hip_runtime.h>

// FitStepOutput: per-row exclusive-prefix cumsum of (1-2*x), argmin (first-min
// tie-break), midpoint of surrounding bin edges.
//
// R4: barrier-free design. Block = 1 wave = 64 rows. LDS is wave-private, so
// no __syncthreads (R3's per-chunk vmcnt(0) drain was the regression). All
// 4 chunks (32 KB) staged up front via 32 fire-and-forget global_load_lds;
// consumption gated by COUNTED s_waitcnt vmcnt(24/16/8/0) — T4 pattern,
// in-order completion (m135). Swizzle: pre-swizzled global source + swizzled
// LDS read (involution, rule #21). 32 KB LDS -> 5 blocks/CU.

#define NBINS  128
#define ROWS   64           // rows per block == threads per block (1 wave)
#define CHUNK  32           // columns per chunk
#define NCHUNK (NBINS / CHUNK)

__global__ __launch_bounds__(ROWS) void fitstep_kernel(
    const float* __restrict__ inp,
    const float* __restrict__ bins,
    float* __restrict__ out,
    int nrows)
{
    __shared__ float lds[NCHUNK][ROWS * CHUNK];   // 4 x 8 KB = 32 KB

    const int t = threadIdx.x;
    const size_t rowbase = (size_t)blockIdx.x * ROWS;

    if (rowbase + ROWS <= (size_t)nrows) {
        const char* base = (const char*)(inp + rowbase * NBINS);

        // Staging map: flat 16B-slot f = i*64 + t  ->  row r = i*8 + (t>>3),
        // dest slot k = t&7.  Source col-slot j = k ^ (r&7) = (t&7)^((t>>3)&7)
        // (constant per thread: i*8 doesn't change r&7).
        const int    jswz     = (t & 7) ^ ((t >> 3) & 7);
        const size_t lanebase = (size_t)(t >> 3) * (NBINS * 4) + (size_t)jswz * 16;

        // Stage ALL 4 chunks, in chunk order (32 outstanding VMEM ops).
        #pragma unroll
        for (int c = 0; c < NCHUNK; ++c) {
            #pragma unroll
            for (int i = 0; i < 8; ++i) {
                __builtin_amdgcn_global_load_lds(
                    (const __attribute__((address_space(1))) unsigned int*)
                        (base + lanebase
                              + (size_t)i * 8 * (NBINS * 4)   // +8 rows per i
                              + (size_t)c * (CHUNK * 4)),     // chunk col offset
                    (__attribute__((address_space(3))) unsigned int*)
                        (&lds[c][(i * ROWS + t) * 4]),
                    16, 0, 0);
            }
            // keep chunk bursts in issue order (vmcnt counting relies on it)
            asm volatile("" ::: "memory");
        }

        float score = 0.0f, best = 0.0f;
        int bestIdx = 0;

        // scan 32 columns of row t from lds[c]; exact np.cumsum order,
        // strict < keeps FIRST minimum (np.argmin semantics).
        auto scan_chunk = [&](int c) {
            #pragma unroll
            for (int j = 0; j < 8; ++j) {
                const int slot = j ^ (t & 7);       // read-side of the swizzle
                float4 v = *reinterpret_cast<const float4*>(
                    &lds[c][t * CHUNK + slot * 4]);
                int colbase = c * CHUNK + j * 4;
                score += (1.0f - 2.0f * v.x);
                if (score < best) { best = score; bestIdx = colbase + 1; }
                score += (1.0f - 2.0f * v.y);
                if (score < best) { best = score; bestIdx = colbase + 2; }
                score += (1.0f - 2.0f * v.z);
                if (score < best) { best = score; bestIdx = colbase + 3; }
                score += (1.0f - 2.0f * v.w);
                if (score < best) { best = score; bestIdx = colbase + 4; }
            }
        };

        // Counted waits: chunk c ready when <= 8*(3-c) loads remain.
        asm volatile("s_waitcnt vmcnt(24)" ::: "memory");
        scan_chunk(0);
        asm volatile("s_waitcnt vmcnt(16)" ::: "memory");
        scan_chunk(1);
        asm volatile("s_waitcnt vmcnt(8)" ::: "memory");
        scan_chunk(2);
        asm volatile("s_waitcnt vmcnt(0)" ::: "memory");
        scan_chunk(3);

        int lo = bestIdx - 1; if (lo < 0) lo = 0;
        int hi = bestIdx;     if (hi > NBINS - 1) hi = NBINS - 1;
        out[rowbase + t] = (bins[lo] + bins[hi]) * 0.5f;
    } else {
        // tail fallback (not hit for B = 1M = 16384 * 64)
        size_t row = rowbase + t;
        if (row >= (size_t)nrows) return;
        const float* rp = inp + row * NBINS;
        float score = 0.0f, best = 0.0f;
        int bestIdx = 0;
        for (int j = 0; j < NBINS; ++j) {
            score += (1.0f - 2.0f * rp[j]);
            if (score < best) { best = score; bestIdx = j + 1; }
        }
        int lo = bestIdx - 1; if (lo < 0) lo = 0;
        int hi = bestIdx;     if (hi > NBINS - 1) hi = NBINS - 1;
        out[row] = (bins[lo] + bins[hi]) * 0.5f;
    }
}

extern "C" void kernel_launch(void* const* d_in, const int* in_sizes, int n_in,
                              void* d_out, int out_size, void* d_ws, size_t ws_size,
                              hipStream_t stream)
{
    const float* inp  = (const float*)d_in[0];
    const float* bins = (const float*)d_in[1];
    float* out = (float*)d_out;

    int nrows = in_sizes[0] / NBINS;   // B = 1048576
    int grid  = (nrows + ROWS - 1) / ROWS;

    fitstep_kernel<<<grid, ROWS, 0, stream>>>(inp, bins, out, nrows);
}